// Round 10
// baseline (211.656 us; speedup 1.0000x reference)
//
#include <hip/hip_runtime.h>
#include <hip/hip_bf16.h>

// Problem constants (from reference setup_inputs)
#define BB    4
#define NTOT  16384
#define CC    256
#define HH    8
#define DD    64
#define HD    512
#define OUTC  256

typedef unsigned short u16;
typedef unsigned int u32;
typedef __attribute__((ext_vector_type(8))) short bf16x8;   // 8 bf16 in 4 VGPRs
typedef __attribute__((ext_vector_type(4))) float f32x4;
typedef __attribute__((ext_vector_type(4))) short u16x4;
typedef __attribute__((ext_vector_type(4))) u32 u32x4;

__device__ __forceinline__ float b2f(u16 u) {
    union { float f; u32 i; } x; x.i = ((u32)u) << 16; return x.f;
}
__device__ __forceinline__ u16 f2b(float f) {
    union { float f; u32 i; } x; x.f = f;
    u32 r = x.i + 0x7fffu + ((x.i >> 16) & 1u);   // round-to-nearest-even
    return (u16)(r >> 16);
}

#define GLD(gp, lp) __builtin_amdgcn_global_load_lds( \
    (const __attribute__((address_space(1))) void*)(gp), \
    (__attribute__((address_space(3))) void*)(lp), 16, 0, 0)

#define MFMA(a, b, c) __builtin_amdgcn_mfma_f32_16x16x32_bf16((a), (b), (c), 0, 0, 0)

// ---------------------------------------------------------------------------
// wcvt: 4 weight matrices (each 131072 f32) -> bf16 + zero Gf (1 MB) and su
// (4 KB) for ggemm's atomics (same stream -> ordering guaranteed).
// grid (64, 1, 4), 256 thr.
// ---------------------------------------------------------------------------
__global__ __launch_bounds__(256) void wcvt(
    const float* __restrict__ Wq, const float* __restrict__ Wk,
    const float* __restrict__ Wv, const float* __restrict__ Wo,
    u16* __restrict__ q, u16* __restrict__ k,
    u16* __restrict__ v, u16* __restrict__ o,
    float* __restrict__ Gf_zero)
{
    const int z = blockIdx.z;
    const float* src = z == 0 ? Wq : z == 1 ? Wk : z == 2 ? Wv : Wo;
    u16* dst = z == 0 ? q : z == 1 ? k : z == 2 ? v : o;
    const int i = (blockIdx.x * 256 + threadIdx.x) * 8;
    const float4 a = *(const float4*)(src + i);
    const float4 b = *(const float4*)(src + i + 4);
    union { bf16x8 v; u16 s[8]; } w;
    w.s[0] = f2b(a.x); w.s[1] = f2b(a.y); w.s[2] = f2b(a.z); w.s[3] = f2b(a.w);
    w.s[4] = f2b(b.x); w.s[5] = f2b(b.y); w.s[6] = f2b(b.z); w.s[7] = f2b(b.w);
    *(bf16x8*)(dst + i) = w.v;

    // zero Gf [4][65536] f32 + su [4][256] f32 = 65792 float4 total
    const int g = (z * 64 + blockIdx.x) * 256 + threadIdx.x;   // 0..65535
    float4* Z = (float4*)Gf_zero;
    Z[g] = float4{0.f, 0.f, 0.f, 0.f};
    if (g < 256) Z[65536 + g] = float4{0.f, 0.f, 0.f, 0.f};
}

// ---------------------------------------------------------------------------
// ggemm v10: v9 (depth-2 reg prefetch, 512-n chunks, XCD-paired halves)
// + ATOMIC epilogue: acc -> atomicAdd into Gf[b] (L2-resident 256 KB/batch,
// 32 contributors/address); su partials -> atomicAdd into su[b]. Eliminates
// the 67 MB Gp round-trip. grid (256), 512 thr, Ts 37.1 KB.
// ---------------------------------------------------------------------------
__global__ __launch_bounds__(512) void ggemm(
    const float* __restrict__ u, float* __restrict__ Gf, float* __restrict__ su,
    u16* __restrict__ u_b)
{
    __shared__ u32 Ts[32 * 290];   // 37.1 KB
    const int z = blockIdx.x;
    const int half = (z >> 3) & 1;               // row-half of the G-tile
    const int cg = ((z >> 4) << 3) | (z & 7);    // chunk 0..127 (z and z^8 pair)
    const int b = cg >> 5, ck = cg & 31;
    const float* base = u + (long long)b * NTOT * CC + (long long)ck * 512 * CC;
    u16* ub_base = u_b + (long long)b * NTOT * CC + (long long)ck * 512 * CC;
    const int t = threadIdx.x, w = t >> 6, l = t & 63;
    const int wy = w >> 2, wx = w & 3;           // 2x4 wave grid over 128x256
    const int r16 = l & 15, quad = l >> 4;
    const int sp = t >> 5;          // n-pair 0..15 (also stages pair sp+16)
    const int sq = t & 31;          // c-octet 0..31

    // column swizzle: col c -> 9*(c>>3) + (c&7); +18 per 16 cols
    const int csa0 = 9 * ((half * 128 + wy * 64 + r16) >> 3) + (r16 & 7);  // +18*i
    const int csb0 = 9 * ((wx * 64 + r16) >> 3) + (r16 & 7);               // +18*j

    f32x4 acc[4][4] = {};
    float su8[8] = {};

    // pf[s][0..1]=row 2sp, [2..3]=row 2sp+1, [4..5]=row 32+2sp, [6..7]=row 33+2sp
    float4 pf[2][8];
#pragma unroll
    for (int s = 0; s < 2; s++) {   // prologue: slabs 0 and 1 in flight
        const float* s1 = base + (long long)(s * 64 + 2 * sp) * CC + sq * 8;
        const float* s2 = s1 + 32 * CC;
        pf[s][0] = *(const float4*)s1;        pf[s][1] = *(const float4*)(s1 + 4);
        pf[s][2] = *(const float4*)(s1 + CC); pf[s][3] = *(const float4*)(s1 + CC + 4);
        pf[s][4] = *(const float4*)s2;        pf[s][5] = *(const float4*)(s2 + 4);
        pf[s][6] = *(const float4*)(s2 + CC); pf[s][7] = *(const float4*)(s2 + CC + 4);
    }

#pragma unroll
    for (int it = 0; it < 8; it++) {
        const int ps = it & 1;      // compile-time after full unroll
        __syncthreads();   // prev iter's frag reads complete (no-op first)
        {   // cvt 4 rows, su8 reg-accum, u_b emit (half0), pair-pack scatter
            union { bf16x8 v; u16 q[8]; } ra, rb, rc, rd;
            ra.q[0] = f2b(pf[ps][0].x); ra.q[1] = f2b(pf[ps][0].y);
            ra.q[2] = f2b(pf[ps][0].z); ra.q[3] = f2b(pf[ps][0].w);
            ra.q[4] = f2b(pf[ps][1].x); ra.q[5] = f2b(pf[ps][1].y);
            ra.q[6] = f2b(pf[ps][1].z); ra.q[7] = f2b(pf[ps][1].w);
            rb.q[0] = f2b(pf[ps][2].x); rb.q[1] = f2b(pf[ps][2].y);
            rb.q[2] = f2b(pf[ps][2].z); rb.q[3] = f2b(pf[ps][2].w);
            rb.q[4] = f2b(pf[ps][3].x); rb.q[5] = f2b(pf[ps][3].y);
            rb.q[6] = f2b(pf[ps][3].z); rb.q[7] = f2b(pf[ps][3].w);
            rc.q[0] = f2b(pf[ps][4].x); rc.q[1] = f2b(pf[ps][4].y);
            rc.q[2] = f2b(pf[ps][4].z); rc.q[3] = f2b(pf[ps][4].w);
            rc.q[4] = f2b(pf[ps][5].x); rc.q[5] = f2b(pf[ps][5].y);
            rc.q[6] = f2b(pf[ps][5].z); rc.q[7] = f2b(pf[ps][5].w);
            rd.q[0] = f2b(pf[ps][6].x); rd.q[1] = f2b(pf[ps][6].y);
            rd.q[2] = f2b(pf[ps][6].z); rd.q[3] = f2b(pf[ps][6].w);
            rd.q[4] = f2b(pf[ps][7].x); rd.q[5] = f2b(pf[ps][7].y);
            rd.q[6] = f2b(pf[ps][7].z); rd.q[7] = f2b(pf[ps][7].w);
            if (half == 0) {
#pragma unroll
                for (int k = 0; k < 8; k++)
                    su8[k] += (b2f(ra.q[k]) + b2f(rb.q[k])) + (b2f(rc.q[k]) + b2f(rd.q[k]));
                u16* ub = ub_base + (long long)(it * 64 + 2 * sp) * CC + sq * 8;
                *(bf16x8*)ub = ra.v;
                *(bf16x8*)(ub + CC) = rb.v;
                *(bf16x8*)(ub + 32 * CC) = rc.v;
                *(bf16x8*)(ub + 33 * CC) = rd.v;
            }
            u32* dst1 = Ts + sp * 290 + 9 * sq;
            u32* dst2 = Ts + (sp + 16) * 290 + 9 * sq;
#pragma unroll
            for (int k = 0; k < 8; k++) {
                dst1[k] = (u32)ra.q[k] | ((u32)rb.q[k] << 16);
                dst2[k] = (u32)rc.q[k] | ((u32)rd.q[k] << 16);
            }
        }
        if (it < 6) {   // reissue consumed set for slab it+2 (2-iter cover)
            const float* s1 = base + (long long)((it + 2) * 64 + 2 * sp) * CC + sq * 8;
            const float* s2 = s1 + 32 * CC;
            pf[ps][0] = *(const float4*)s1;        pf[ps][1] = *(const float4*)(s1 + 4);
            pf[ps][2] = *(const float4*)(s1 + CC); pf[ps][3] = *(const float4*)(s1 + CC + 4);
            pf[ps][4] = *(const float4*)s2;        pf[ps][5] = *(const float4*)(s2 + 4);
            pf[ps][6] = *(const float4*)(s2 + CC); pf[ps][7] = *(const float4*)(s2 + CC + 4);
        }
        __syncthreads();

#pragma unroll
        for (int kb = 0; kb < 2; kb++) {   // two K=32 sub-blocks of the slab
            const int pr0 = (kb * 16 + 4 * quad) * 290;
            bf16x8 a[4], bb[4];
#pragma unroll
            for (int i = 0; i < 4; i++) {
                const int cs = pr0 + csa0 + 18 * i;
                union { u32x4 u4; bf16x8 h; } f;
                f.u4[0] = Ts[cs];       f.u4[1] = Ts[290 + cs];
                f.u4[2] = Ts[580 + cs]; f.u4[3] = Ts[870 + cs];
                a[i] = f.h;
            }
#pragma unroll
            for (int j = 0; j < 4; j++) {
                const int cs = pr0 + csb0 + 18 * j;
                union { u32x4 u4; bf16x8 h; } f;
                f.u4[0] = Ts[cs];       f.u4[1] = Ts[290 + cs];
                f.u4[2] = Ts[580 + cs]; f.u4[3] = Ts[870 + cs];
                bb[j] = f.h;
            }
#pragma unroll
            for (int i = 0; i < 4; i++)
#pragma unroll
                for (int j = 0; j < 4; j++)
                    acc[i][j] = MFMA(a[i], bb[j], acc[i][j]);
        }
    }

    // atomic reduce into Gf[b] (L2-resident; 32 contributors per address)
    float* Cp = Gf + (long long)b * 65536;
#pragma unroll
    for (int i = 0; i < 4; i++)
#pragma unroll
        for (int j = 0; j < 4; j++)
#pragma unroll
            for (int rr = 0; rr < 4; rr++)
                atomicAdd(&Cp[(half * 128 + wy * 64 + 16 * i + quad * 4 + rr) * 256
                              + wx * 64 + 16 * j + r16], acc[i][j][rr]);

    if (half == 0) {   // su reduce via Ts scratch, then one atomic per channel
        __syncthreads();
        float* S = (float*)Ts;   // [16][264] f32 = 16.9 KB < 37.1 KB
#pragma unroll
        for (int k = 0; k < 8; k++) S[sp * 264 + sq * 8 + k] = su8[k];
        __syncthreads();
        if (t < 256) {
            float s = 0.f;
#pragma unroll
            for (int p = 0; p < 16; p++) s += S[p * 264 + t];
            atomicAdd(&su[b * 256 + t], s);
        }
    }
}

// ---------------------------------------------------------------------------
// gcvt: Gb = bf16(Gf) -- 1 MB convert (replaces the 34 MB gred reduction).
// grid (64, 4), 256 thr.
// ---------------------------------------------------------------------------
__global__ __launch_bounds__(256) void gcvt(
    const float* __restrict__ Gf, u16* __restrict__ Gb)
{
    const int b = blockIdx.y, t = threadIdx.x;
    const int row = blockIdx.x * 4 + (t >> 6);
    const int col = (t & 63) * 4;
    const long long idx = (long long)b * 65536 + row * 256 + col;
    f32x4 v = *(const f32x4*)(Gf + idx);
    union { u16x4 v; u16 q[4]; } pk;
#pragma unroll
    for (int k = 0; k < 4; k++) pk.q[k] = f2b(v[k]);
    *(u16x4*)(Gb + idx) = pk.v;
}

// ---------------------------------------------------------------------------
// skvz: serial tail per (b,h). Inputs: P2 = [Wk;Wv]_stacked x G (bf16), su.
// stats via direct row-dots; S = Pk Wv^T (frags from global); kv -> kvT LDS;
// WqT staging + Y-phase. grid (32), 256 thr.
// ---------------------------------------------------------------------------
__global__ __launch_bounds__(256) void skvz(
    const u16* __restrict__ P2, const float* __restrict__ su,
    const u16* __restrict__ Wk_b, const u16* __restrict__ Wv_b,
    const u16* __restrict__ Wq_b, u16* __restrict__ Zt)
{
    __shared__ u16 pool[20480];   // kvTL 8KB + WqTL 32KB
    __shared__ float mkL[64], rkL[64], mvL[64], rvL[64];

    const int bx = blockIdx.x, b = bx >> 3, h = bx & 7;
    const int t = threadIdx.x, w = t >> 6, l = t & 63;
    const int r16 = l & 15, quad = l >> 4;

    const u16* WkH = Wk_b + (h * 64) * 256;
    const u16* WvH = Wv_b + (h * 64) * 256;
    const u16* PkH = P2 + (long long)b * 262144 + (h * 64) * 256;
    const u16* PvH = P2 + (long long)b * 262144 + (512 + h * 64) * 256;

    // ---- stats: 2 threads per row (128 rows: 64 k + 64 v) ----
    {
        const int row = t >> 1, half = t & 1;
        const u16* Prow = (row < 64 ? PkH + row * 256 : PvH + (row - 64) * 256) + half * 128;
        const u16* Wrow = (row < 64 ? WkH + row * 256 : WvH + (row - 64) * 256) + half * 128;
        const float* suB = su + b * 256 + half * 128;
        float e2 = 0.f, m = 0.f;
#pragma unroll
        for (int c8 = 0; c8 < 16; c8++) {
            bf16x8 pw = *(const bf16x8*)(Prow + c8 * 8);
            bf16x8 ww = *(const bf16x8*)(Wrow + c8 * 8);
#pragma unroll
            for (int k = 0; k < 8; k++) {
                const float wv_ = b2f((u16)ww[k]);
                e2 += b2f((u16)pw[k]) * wv_;
                m  += wv_ * suB[c8 * 8 + k];
            }
        }
        e2 += __shfl_xor(e2, 1);
        m  += __shfl_xor(m, 1);
        if (half == 0) {
            m *= (1.0f / NTOT);
            const float r = rsqrtf(e2 * (1.0f / NTOT) - m * m + 1e-5f);
            if (row < 64) { mkL[row] = m; rkL[row] = r; }
            else          { mvL[row - 64] = m; rvL[row - 64] = r; }
        }
    }
    __syncthreads();

    // ---- S-phase: S[d,e] = sum_c Pk[d,c] Wv[e,c]; frags from global ----
    const int mh = (w >> 1) * 32, nh = (w & 1) * 32;
    float mkR[2][4], rkR[2][4], mvR[2], rvR[2];
#pragma unroll
    for (int i = 0; i < 2; i++)
#pragma unroll
        for (int rr = 0; rr < 4; rr++) {
            mkR[i][rr] = mkL[mh + 16 * i + quad * 4 + rr];
            rkR[i][rr] = rkL[mh + 16 * i + quad * 4 + rr];
        }
#pragma unroll
    for (int j = 0; j < 2; j++) {
        mvR[j] = mvL[nh + 16 * j + r16];
        rvR[j] = rvL[nh + 16 * j + r16];
    }

    f32x4 accs[2][2] = {};
    for (int ch = 0; ch < 8; ch++) {
        const int ko = quad * 8;
        bf16x8 ap[2], bv[2];
#pragma unroll
        for (int i = 0; i < 2; i++)
            ap[i] = *(const bf16x8*)(PkH + (mh + 16 * i + r16) * 256 + ch * 32 + ko);
#pragma unroll
        for (int j = 0; j < 2; j++)
            bv[j] = *(const bf16x8*)(WvH + (nh + 16 * j + r16) * 256 + ch * 32 + ko);
#pragma unroll
        for (int i = 0; i < 2; i++)
#pragma unroll
            for (int j = 0; j < 2; j++)
                accs[i][j] = MFMA(ap[i], bv[j], accs[i][j]);
    }

    // ---- kv -> kvTL; WqTL ----
    u16* kvTL = pool;            // 8 KB
    u16* WqTL = pool + 4096;     // 32 KB
#pragma unroll
    for (int i = 0; i < 2; i++)
#pragma unroll
        for (int j = 0; j < 2; j++)
#pragma unroll
            for (int rr = 0; rr < 4; rr++) {
                const int d = mh + 16 * i + quad * 4 + rr;
                const int e = nh + 16 * j + r16;
                const float kv = rkR[i][rr] * rvR[j] *
                    (accs[i][j][rr] * (1.0f / NTOT) - mkR[i][rr] * mvR[j]);
                kvTL[(d >> 5) * 2048 + e * 32 + (d & 31)] = f2b(kv);
            }
    {
        const int d = t >> 2, q = t & 3;
        const u16* Wrow = Wq_b + (h * 64 + d) * 256 + q * 64;
#pragma unroll
        for (int s = 0; s < 8; s++) {
            bf16x8 raw = *(const bf16x8*)(Wrow + s * 8);
#pragma unroll
            for (int k = 0; k < 8; k++) {
                const int c = q * 64 + s * 8 + k;
                WqTL[(d >> 5) * 8192 + c * 32 + (d & 31)] = (u16)raw[k];
            }
        }
    }
    __syncthreads();

    // ---- Y-phase ----
    f32x4 accy[4][4] = {};
#pragma unroll
    for (int ch = 0; ch < 2; ch++) {
        const int ko = quad * 8;
        bf16x8 akv[4], bq[4];
#pragma unroll
        for (int i = 0; i < 4; i++)
            akv[i] = *(const bf16x8*)(kvTL + ch * 2048 + (16 * i + r16) * 32 + ko);
#pragma unroll
        for (int j = 0; j < 4; j++)
            bq[j] = *(const bf16x8*)(WqTL + ch * 8192 + (w * 64 + 16 * j + r16) * 32 + ko);
#pragma unroll
        for (int i = 0; i < 4; i++)
#pragma unroll
            for (int j = 0; j < 4; j++)
                accy[i][j] = MFMA(akv[i], bq[j], accy[i][j]);
    }
#pragma unroll
    for (int i = 0; i < 4; i++)
#pragma unroll
        for (int j = 0; j < 4; j++) {
            const int c = w * 64 + 16 * j + r16;
            const int e0 = 16 * i + quad * 4;
            union { u16x4 v; u16 s[4]; } pk;
#pragma unroll
            for (int rr = 0; rr < 4; rr++) pk.s[rr] = f2b(accy[i][j][rr]);
            *(u16x4*)(Zt + ((long long)(b * 256 + c)) * 512 + h * 64 + e0) = pk.v;
        }
}

// ---------------------------------------------------------------------------
// gemm_bt (proven, r2): C[m,n] = sum_k A[m,k]*Bm[n,k] (+bias[n]); bf16 A,B.
// ---------------------------------------------------------------------------
template <typename CT>
__global__ __launch_bounds__(256) void gemm_bt(
    const u16* __restrict__ A, const u16* __restrict__ Bm,
    CT* __restrict__ C, const float* __restrict__ bias,
    int K, int lda, int ldc,
    long long aStride, long long bStride, long long cStride)
{
    __shared__ u16 As[128 * 32];
    __shared__ u16 Bs[128 * 32];

    const int bz = blockIdx.z;
    A  += (long long)bz * aStride;
    Bm += (long long)bz * bStride;
    C  += (long long)bz * cStride;

    const int m0 = blockIdx.x * 128;
    const int n0 = blockIdx.y * 128;
    const int t  = threadIdx.x;
    const int wv = t >> 6, l = t & 63;
    const int wy = wv >> 1, wx = wv & 1;
    const int r16  = l & 15;
    const int quad = l >> 4;
    const int srow = wv * 16 + (l >> 2);
    const int scol = (l & 3) * 8;

    f32x4 acc[4][4] = {};

    for (int kk = 0; kk < K; kk += 32) {
#pragma unroll
        for (int s = 0; s < 2; s++) {
            GLD(A + (long long)(m0 + s * 64 + srow) * lda + kk + scol,
                As + s * 2048 + wv * 512);
            GLD(Bm + (long long)(n0 + s * 64 + srow) * K + kk + scol,
                Bs + s * 2048 + wv * 512);
        }
        __syncthreads();

        bf16x8 a[4], b[4];
#pragma unroll
        for (int i = 0; i < 4; i++)
            a[i] = *(const bf16x8*)(As + (wy * 64 + 16 * i + r16) * 32 + quad * 8);
#pragma unroll
        for (int j = 0; j < 4; j++)
            b[j] = *(const bf16x8*)(Bs + (wx * 64 + 16 * j + r16) * 32 + quad * 8);
#pragma unroll
        for (int i = 0; i < 4; i++)
#pragma unroll
            for (int j = 0; j < 4; j++)
                acc[i][j] = MFMA(a[i], b[j], acc[i][j]);
        __syncthreads();
    }

#pragma unroll
    for (int j = 0; j < 4; j++) {
        const int col = n0 + wx * 64 + 16 * j + r16;
        const float bv = bias ? bias[col] : 0.0f;
#pragma unroll
        for (int i = 0; i < 4; i++) {
#pragma unroll
            for (int r = 0; r < 4; r++) {
                const int row = m0 + wy * 64 + 16 * i + quad * 4 + r;
                const float v = acc[i][j][r] + bv;
                if constexpr (sizeof(CT) == 2) C[(long long)row * ldc + col] = f2b(v);
                else                           C[(long long)row * ldc + col] = v;
            }
        }
    }
}

// ---------------------------------------------------------------------------
// gemm_out v3 (proven, r6): out[n,o] = sum_c u_b[n,c]*Ft[o,c] + bo[o].
// 1024 thr, 16 waves (4x4), 32x64 per wave, acc[2][4]. grid (128, 1, 4).
// ---------------------------------------------------------------------------
__global__ __launch_bounds__(1024) void gemm_out(
    const u16* __restrict__ Au, const u16* __restrict__ Ft,
    float* __restrict__ C, const float* __restrict__ bias)
{
    __shared__ u16 As[128 * 32];   // 8 KB
    __shared__ u16 Bs[256 * 32];   // 16 KB

    const int b = blockIdx.z;
    Au += (long long)b * NTOT * CC;
    const u16* Bm = Ft + (long long)b * 65536;
    C += (long long)b * NTOT * OUTC;

    const int m0 = blockIdx.x * 128;
    const int t  = threadIdx.x;
    const int wv = t >> 6, l = t & 63;
    const int wy = wv >> 2, wx = wv & 3;   // 4x4 wave grid, 32x64 each
    const int r16  = l & 15;
    const int quad = l >> 4;
    const int srow = t >> 2;               // staging row
    const int scol = (t & 3) * 8;          // staging col (8 bf16 = 16 B)

    f32x4 acc[2][4] = {};

    for (int kk = 0; kk < 256; kk += 32) {
        // B: 256x32 staged by all 1024 thr (1 GLD, dest byte = 16*t: linear)
        GLD(Bm + (long long)srow * 256 + kk + scol, Bs + srow * 32 + scol);
        // A: 128x32 staged by waves 0..7 (t<512; wave-uniform branch)
        if (t < 512)
            GLD(Au + (long long)(m0 + srow) * CC + kk + scol, As + srow * 32 + scol);
        __syncthreads();

        bf16x8 a[2], bb[4];
#pragma unroll
        for (int i = 0; i < 2; i++)
            a[i] = *(const bf16x8*)(As + (wy * 32 + 16 * i + r16) * 32 + quad * 8);
#pragma unroll
        for (int j = 0; j < 4; j++)
            bb[j] = *(const bf16x8*)(Bs + (wx * 64 + 16 * j + r16) * 32 + quad * 8);
#pragma unroll
        for (int i = 0; i < 2; i++)
#pragma unroll
            for (int j = 0; j < 4; j++)
                acc[i][j] = MFMA(a[i], bb[j], acc[i][j]);
        __syncthreads();
    }

#pragma unroll
    for (int j = 0; j < 4; j++) {
        const int col = wx * 64 + 16 * j + r16;
        const float bv = bias[col];
#pragma unroll
        for (int i = 0; i < 2; i++) {
#pragma unroll
            for (int r = 0; r < 4; r++) {
                const int row = m0 + wy * 32 + 16 * i + quad * 4 + r;
                C[(long long)row * OUTC + col] = acc[i][j][r] + bv;
            }
        }
    }
}

// ---------------------------------------------------------------------------
extern "C" void kernel_launch(void* const* d_in, const int* in_sizes, int n_in,
                              void* d_out, int out_size, void* d_ws, size_t ws_size,
                              hipStream_t stream)
{
    const float* u_src = (const float*)d_in[0];
    // d_in[1] = pos_src (unused)
    const float* Wq = (const float*)d_in[2];
    const float* Wk = (const float*)d_in[3];
    const float* Wv = (const float*)d_in[4];
    const float* Wo = (const float*)d_in[5];
    const float* bo = (const float*)d_in[6];
    float* out = (float*)d_out;

    char* ws = (char*)d_ws;
    size_t off = 0;
    float* Gf  = (float*)(ws + off); off += 1048576;   // [4][256][256] f32 (atomic target)
    float* su  = (float*)(ws + off); off += 4096;      // [4][256] f32 (atomic target; contiguous after Gf for wcvt zeroing)
    u16*  Gb   = (u16*)(ws + off);  off += 524288;     // [4][256][256] bf16
    u16*  Wq_b = (u16*)(ws + off);  off += 262144;
    u16*  Wk_b = (u16*)(ws + off);  off += 262144;     // adjacent to Wv_b -> stacked [1024][256]
    u16*  Wv_b = (u16*)(ws + off);  off += 262144;
    u16*  Wo_b = (u16*)(ws + off);  off += 262144;     // [256][512] bf16
    u16*  Zt   = (u16*)(ws + off);  off += 1048576;    // [4][256][512] bf16
    u16*  Ft   = (u16*)(ws + off);  off += 524288;     // [4][256][256] bf16
    u16*  P2   = (u16*)(ws + off);  off += 2097152;    // [4][1024][256] bf16 ([Wk;Wv] x G)
    u16*  u_b  = (u16*)(ws + off);  off += 33554432;   // [4][16384][256] bf16 (side product)

    const dim3 blk(256);

    // weights -> bf16 + zero Gf/su for atomics
    wcvt<<<dim3(64, 1, 4), blk, 0, stream>>>(Wq, Wk, Wv, Wo, Wq_b, Wk_b, Wv_b, Wo_b, Gf);

    // G via atomic reduce (512-n chunks, XCD-paired halves) + su + u_b emit
    ggemm<<<dim3(256), dim3(512), 0, stream>>>(u_src, Gf, su, u_b);
    gcvt<<<dim3(64, BB), blk, 0, stream>>>(Gf, Gb);

    // P2[b] = [Wk;Wv]_stacked (1024x256) x G_b (G symmetric -> B^T form exact)
    gemm_bt<u16><<<dim3(8, 2, BB), blk, 0, stream>>>(
        Wk_b, Gb, P2, nullptr, 256, 256, 256, 0, 65536, 262144);

    // stats/S/kv/Zt (short serial tail)
    skvz<<<dim3(BB * HH), blk, 0, stream>>>(P2, su, Wk_b, Wv_b, Wq_b, Zt);

    // Ft[b] = Wo Zt_b^T : [256x512]x[512x256]
    gemm_bt<u16><<<dim3(2, 2, BB), blk, 0, stream>>>(
        Wo_b, Zt, Ft, nullptr, 512, 512, 256, 0, 131072, 65536);

    // out = u_b Ft^T + bo (bf16 A via GLD, 16-wave low-acc block)
    gemm_out<<<dim3(128, 1, BB), dim3(1024), 0, stream>>>(u_b, Ft, out, bo);
}